// Round 12
// baseline (795.032 us; speedup 1.0000x reference)
//
#include <hip/hip_runtime.h>
#include <stdint.h>

// Problem constants
#define N_ROWS 8192
#define D_DIM  1024
#define M_CENT 20000
#define M_PAD  20224          // 79 * 256
#define M_TILES 79            // 256-wide center tiles
#define Y_DIM  256
#define BM 64                 // rows of X per block (2 blocks/CU geometry)
#define BN 256                // centers per M-iteration (wave tile 64x64)
#define BK 32                 // K-chunk of D
#define NCHUNK 32             // D_DIM / BK
#define MSPLIT 8
#define TILES_PER_SPLIT 10    // ceil(79/8)
#define LDSP_STRIDE 264       // 256 + 8 pad: 33 16B-slots/row == 1 mod 8 -> conflict-free

// LDS layout (u16 element offsets into lds_all), R14 4-buffer rotation:
//   buf k: [k*10240, (k+1)*10240), k = 0..3           (4 x 20480 B = 81920 B)
//   p    : [20480, 37376)  = P[64][264] -- aliases buf2 + buf3-head.
//   norms: [37376, 38016)  = xsq f32[64] + zsq f32[256] -- buf3 TAIL GAP,
//          written at the phase1->2 boundary (the unique point where buf3 is
//          stable: chunk-31's vmcnt retired stage(c31), barrier synced, and
//          buf3 is not re-staged until next tile's chunk 1).
// Total = EXACTLY 81920 B (= R7/R8's HW-verified 2-blocks/CU footprint).
#define BUFE 10240            // elements per stage buffer
#define ZOFFE 2048            // Z offset within a buffer
#define POFF 20480            // p region start (== buf2)
#define XGOFF 37376           // xsq gap (64 f32 = 128 elem)
#define ZGOFF 37504           // zsq gap (256 f32 = 512 elem), ends 38016

typedef __attribute__((ext_vector_type(4))) float  f32x4;
typedef __attribute__((ext_vector_type(8))) __bf16 bf16x8;

__device__ __forceinline__ unsigned short f2bf(float f) {
    union { float f; unsigned u; } v; v.f = f;
    unsigned u = v.u;
    u += 0x7FFFu + ((u >> 16) & 1u);   // RNE
    return (unsigned short)(u >> 16);
}

// async global->LDS, 16B per lane. LDS dest must be wave-uniform base + lane*16.
__device__ __forceinline__ void gll16(void* lds, const void* g) {
    __builtin_amdgcn_global_load_lds(
        (const __attribute__((address_space(1))) void*)g,
        (__attribute__((address_space(3))) void*)lds, 16, 0, 0);
}

// cast fp32 rows -> bf16, compute fp32 row sum-of-squares; pad rows -> zeros
__global__ void cast_rows_kernel(const float* __restrict__ src,
                                 unsigned short* __restrict__ dst,
                                 float* __restrict__ sq, int nrows_valid) {
    int row = blockIdx.x;
    int t = threadIdx.x;  // 256 threads, 4 floats each = 1024 = D_DIM
    float s = 0.f;
    if (row < nrows_valid) {
        float4 v = ((const float4*)(src + (size_t)row * D_DIM))[t];
        s = v.x * v.x + v.y * v.y + v.z * v.z + v.w * v.w;
        ushort4 o;
        o.x = f2bf(v.x); o.y = f2bf(v.y); o.z = f2bf(v.z); o.w = f2bf(v.w);
        ((ushort4*)(dst + (size_t)row * D_DIM))[t] = o;
    } else {
        ((ushort4*)(dst + (size_t)row * D_DIM))[t] = make_ushort4(0, 0, 0, 0);
    }
    __shared__ float red[4];
    for (int off = 32; off; off >>= 1) s += __shfl_down(s, off, 64);
    if ((t & 63) == 0) red[t >> 6] = s;
    __syncthreads();
    if (t == 0) sq[row] = red[0] + red[1] + red[2] + red[3];
}

// W [M][Y] fp32 -> WT [Y][M_PAD] bf16, pad rows (centers >= M_CENT) -> 0
__global__ void cast_wT_kernel(const float* __restrict__ w,
                               unsigned short* __restrict__ wT) {
    __shared__ float tile[32][33];
    int k0 = blockIdx.x * 32;   // center dim
    int y0 = blockIdx.y * 32;   // Y dim
    int tx = threadIdx.x & 31;
    int ty = threadIdx.x >> 5;  // 0..7
    #pragma unroll
    for (int i = 0; i < 4; ++i) {
        int k = k0 + ty + i * 8;
        float v = (k < M_CENT) ? w[(size_t)k * Y_DIM + y0 + tx] : 0.f;
        tile[tx][ty + i * 8] = v;     // tile[y_local][k_local]
    }
    __syncthreads();
    #pragma unroll
    for (int i = 0; i < 4; ++i) {
        int yl = ty + i * 8;
        wT[(size_t)(y0 + yl) * M_PAD + k0 + tx] = f2bf(tile[yl][tx]);
    }
}

// ---------------------------------------------------------------------------
// R14 (post-mortem R13: conflicts fixed, no spill, but 677us -- BK=32's real
// costs are 66 barriers/tile (vs R8's 34) and ~1-chunk prefetch slack (~200
// cyc, under L2 latency) -> exposed stall every chunk.  4xBK32 bufs = 2xBK64
// bufs = EXACTLY 81920B, so a 4-buffer rotation buys depth-2 + 1 barrier/chunk
// while keeping the no-spill LDS-norm shape):
//  - Chunk kc: STAGE(kc+2 -> buf[(kc+2)%4]); vmcnt(10) (queue = 3x5 stage
//    ops; waits exactly stage(kc), issued TWO chunks ago -> R8-level slack);
//    ONE s_barrier; 8 ds_read; 16 MFMA.  Stage-before-barrier safe: the
//    target's readers were chunk kc-2, complete once any wave passed chunk
//    kc-1's barrier (reads precede that chunk's MFMAs precede arrival).
//  - p aliases buf2+buf3-head; during Phases 2-3 only buf0/buf1 are prefetch
//    targets (chunks 30/31 stage next-tile c0/c1) -> disjoint.  Hazards
//    closed by 3 per-tile barriers: phase1->2 (p overwrite vs chunk-30/31
//    reads), phase2->3 (p write->read), tile-end (next chunk-0 stage vs
//    phase-3 p reads).  Barriers/tile: 32 + 3 = 35.
//  - Norms -> buf3 tail gap at the phase1->2 boundary (transient reg ->
//    ds_write, R13's proven no-spill pattern).  Boundary loads make the
//    compiler drain the nt0/nt1 prefetch (~100s of cyc, once per tile,
//    accepted); they still land long before next tile's chunk 0.
//  - R13 swizzle kept ((row>>1)&3 / swl).  launch_bounds(256,2), MSPLIT=8.
//  Sentinels: WRITE ~68MB (no spill), LDS 81920, conflicts ~5.2M.
//  Fork: clean but >=640us -> staging throughput is structural -> BM=128.
// ---------------------------------------------------------------------------

#define STAGE(BUF, M0, KBASE) do {                                            \
    { int lin_ = t; int row_ = lin_ >> 2, c_ = lin_ & 3;   /* X: 256 units */ \
      gll16(&lds_all[(BUF) * BUFE + lin_ * 8],                                \
            Xb + (size_t)(row0 + row_) * D_DIM + (KBASE) +                    \
                ((c_ ^ ((row_ >> 1) & 3)) * 8)); }                            \
    _Pragma("unroll")                                                         \
    for (int i_ = 0; i_ < 4; ++i_) {          /* Z: 1024 units */             \
        int lin_ = t + i_ * 256;                                              \
        int row_ = lin_ >> 2, c_ = lin_ & 3;                                  \
        gll16(&lds_all[(BUF) * BUFE + ZOFFE + lin_ * 8],                      \
              Zb + (size_t)((M0) + row_) * D_DIM + (KBASE) +                  \
                  ((c_ ^ ((row_ >> 1) & 3)) * 8));                            \
    } } while (0)

// One K-chunk.  RD = kc%4 (read buf), ST = (kc+2)%4 (stage buf), literals.
// On entry: [stage(kc):5][stage(kc+1):5] outstanding.  After STAGE: 15 ops;
// vmcnt(10) waits exactly stage(kc) (2-chunk slack).  In-order retirement
// makes the count robust to older stray loads (they drain first).
#define CHUNK(RD, ST, M0S, KBS) do {                                          \
    asm volatile("" ::: "memory");                                            \
    STAGE(ST, M0S, KBS);                                                      \
    __builtin_amdgcn_sched_barrier(0);                                        \
    asm volatile("s_waitcnt vmcnt(10)" ::: "memory"); /* stage(kc) done */    \
    __builtin_amdgcn_s_barrier();          /* everyone's stage(kc) done */    \
    asm volatile("" ::: "memory");                                            \
    bf16x8 a_[4], b_[4];                                                      \
    _Pragma("unroll")                                                         \
    for (int it_ = 0; it_ < 4; ++it_)                                         \
        a_[it_] = *(const bf16x8*)&lds_all[(RD) * BUFE +                      \
            (it_ * 16 + l16) * BK + swl];                                     \
    _Pragma("unroll")                                                         \
    for (int jt_ = 0; jt_ < 4; ++jt_)                                         \
        b_[jt_] = *(const bf16x8*)&lds_all[(RD) * BUFE + ZOFFE +              \
            (wave * 64 + jt_ * 16 + l16) * BK + swl];                         \
    __builtin_amdgcn_s_setprio(1);                                            \
    _Pragma("unroll")                                                         \
    for (int it_ = 0; it_ < 4; ++it_)                                         \
        _Pragma("unroll")                                                     \
        for (int jt_ = 0; jt_ < 4; ++jt_)                                     \
            S[it_ * 4 + jt_] = __builtin_amdgcn_mfma_f32_16x16x32_bf16(       \
                a_[it_], b_[jt_], S[it_ * 4 + jt_], 0, 0, 0);                 \
    __builtin_amdgcn_s_setprio(0);                                            \
  } while (0)

__global__ void __launch_bounds__(256, 2)
fused_kernel(const unsigned short* __restrict__ Xb,
             const unsigned short* __restrict__ Zb,
             const unsigned short* __restrict__ WbT,
             const float* __restrict__ xsq,
             const float* __restrict__ zsq,
             const int* __restrict__ bwp,
             float* __restrict__ out) {
    __shared__ unsigned short lds_all[4 * BUFE];   // EXACTLY 81920 B
    float* xg = (float*)&lds_all[XGOFF];           // gap-resident xsq[64]
    float* zg = (float*)&lds_all[ZGOFF];           // gap-resident zsq[256]

    const int t    = threadIdx.x;
    const int wave = t >> 6;      // 0..3: m-slab (phase1 B, phase3 y-slab)
    const int lane = t & 63;
    const int quad = lane >> 4;
    const int l16  = lane & 15;
    const int swl  = (quad ^ ((l16 >> 1) & 3)) * 8;  // R13 verified swizzle

    const int row0 = blockIdx.x * BM;          // R2 known-good mapping
    const int mt0  = blockIdx.y * TILES_PER_SPLIT;
    int mt_end = mt0 + TILES_PER_SPLIT;
    if (mt_end > M_TILES) mt_end = M_TILES;

    // bandwidth: int32 per harness convention (Python int 10); tolerate float bits too
    int bwi = *bwp;
    float bw;
    if (bwi > 0 && bwi < 1000000) bw = (float)bwi;
    else { union { int i; float f; } u; u.i = bwi; bw = u.f; }
    const float inv_bw = 1.0f / bw;

    const f32x4 vzero = {0.f, 0.f, 0.f, 0.f};
    f32x4 Oacc[16];
    #pragma unroll
    for (int i = 0; i < 16; ++i) Oacc[i] = vzero;

    // prologue: stage chunks 0,1 of the first tile -> buf0, buf1
    STAGE(0, mt0 * BN, 0);
    STAGE(1, mt0 * BN, BK);
    __builtin_amdgcn_sched_barrier(0);

    for (int mt = mt0; mt < mt_end; ++mt) {
        const int m0 = mt * BN;
        // last tile of split prefetches itself (valid mem, unused)
        const int m0next = (mt + 1 < mt_end) ? m0 + BN : m0;

        f32x4 S[16];
        #pragma unroll
        for (int i = 0; i < 16; ++i) S[i] = vzero;

        // -------- Phase 1: S[64x256] = X * Z^T, depth-2 4-buf pipeline ----
        // chunk kc reads buf[kc%4], stages chunk kc+2 into buf[(kc+2)%4].
        // kc=30,31 stage next tile's chunks 0,1 into buf0,buf1 (disjoint
        // from p) -> they land during Phases 2-3.
        #pragma unroll 1
        for (int kc = 0; kc < NCHUNK; kc += 4) {
            const bool tl = (kc == NCHUNK - 4);
            CHUNK(0, 2, m0, (kc + 2) * BK);
            CHUNK(1, 3, m0, (kc + 3) * BK);
            CHUNK(2, 0, tl ? m0next : m0, tl ? 0 : (kc + 4) * BK);
            CHUNK(3, 1, tl ? m0next : m0, tl ? BK : (kc + 5) * BK);
        }

        // ---- phase1 -> 2 boundary ----
        // buf2/buf3 stable here (chunk-30/31 vmcnts retired their stages;
        // their readers passed the last chunk barriers).  Write norms into
        // the buf3 tail gap (transient regs; compiler's wait for these
        // loads drains the nt prefetch -- accepted, once per tile).
        {
            float tZ = zsq[m0 + t];                       // BN == blockDim
            float tX = (t < BM) ? xsq[row0 + t] : 0.f;
            zg[t] = tZ;
            if (t < BM) xg[t] = tX;
        }
        asm volatile("s_waitcnt lgkmcnt(0)" ::: "memory");
        __builtin_amdgcn_s_barrier();   // norms visible; buf2/3 readers done
        asm volatile("" ::: "memory");

        // -------- Phase 2: P = exp(-sqrt(d2)/bw) -> p (bf16) --------
        #pragma unroll
        for (int it = 0; it < 4; ++it) {
            #pragma unroll
            for (int jt = 0; jt < 4; ++jt) {
                f32x4 s4 = S[it * 4 + jt];
                const int col = wave * 64 + jt * 16 + l16;
                const float zq = zg[col];
                #pragma unroll
                for (int r = 0; r < 4; ++r) {
                    const int row = it * 16 + quad * 4 + r;   // C-layout
                    float d2 = xg[row] + zq - 2.0f * s4[r];
                    d2 = fmaxf(d2, 0.f);
                    float d;
                    asm("v_sqrt_f32 %0, %1" : "=v"(d) : "v"(d2));
                    float p = __expf(-d * inv_bw);
                    lds_all[POFF + row * LDSP_STRIDE + col] = f2bf(p);
                }
            }
        }
        // P-write -> P-read: LDS-only drain; buf0/1 prefetch unaffected
        asm volatile("s_waitcnt lgkmcnt(0)" ::: "memory");
        __builtin_amdgcn_s_barrier();
        asm volatile("" ::: "memory");

        // -------- Phase 3: O += P[64x256] * Wtile[256x256] --------
        #pragma unroll
        for (int ks = 0; ks < 8; ++ks) {
            const int koff = ks * 32 + quad * 8;
            bf16x8 a[4], b[4];
            #pragma unroll
            for (int rt = 0; rt < 4; ++rt)
                a[rt] = *(const bf16x8*)&lds_all[POFF +
                    (rt * 16 + l16) * LDSP_STRIDE + koff];
            #pragma unroll
            for (int ct = 0; ct < 4; ++ct) {
                const int y = wave * 64 + ct * 16 + l16;
                b[ct] = *(const bf16x8*)(WbT + (size_t)y * M_PAD + m0 + koff);
            }
            __builtin_amdgcn_s_setprio(1);
            #pragma unroll
            for (int rt = 0; rt < 4; ++rt)
                #pragma unroll
                for (int ct = 0; ct < 4; ++ct)
                    Oacc[rt * 4 + ct] = __builtin_amdgcn_mfma_f32_16x16x32_bf16(
                        a[rt], b[ct], Oacc[rt * 4 + ct], 0, 0, 0);
            __builtin_amdgcn_s_setprio(0);
        }

        // tile-end barrier: next tile's chunk-0 STAGE targets buf2 (= old p);
        // all waves' phase-3 p reads complete before their arrival here.
        asm volatile("" ::: "memory");
        __builtin_amdgcn_s_barrier();
        asm volatile("" ::: "memory");
    }

    // drain any dangling prefetch before LDS is released
    asm volatile("s_waitcnt vmcnt(0)" ::: "memory");

    // -------- epilogue: accumulate M-splits via device-scope fp32 atomics ----
    #pragma unroll
    for (int rt = 0; rt < 4; ++rt) {
        #pragma unroll
        for (int ct = 0; ct < 4; ++ct) {
            f32x4 v = Oacc[rt * 4 + ct];
            const int y = wave * 64 + ct * 16 + l16;
            #pragma unroll
            for (int r = 0; r < 4; ++r) {
                const int row = row0 + rt * 16 + quad * 4 + r;
                atomicAdd(&out[(size_t)row * Y_DIM + y], v[r]);
            }
        }
    }
}

extern "C" void kernel_launch(void* const* d_in, const int* in_sizes, int n_in,
                              void* d_out, int out_size, void* d_ws, size_t ws_size,
                              hipStream_t stream) {
    const float* X = (const float*)d_in[0];
    const float* Z = (const float*)d_in[1];
    const float* W = (const float*)d_in[2];
    const int*  bw = (const int*)d_in[3];
    float* out = (float*)d_out;

    char* ws = (char*)d_ws;
    size_t off = 0;
    unsigned short* Xb  = (unsigned short*)(ws + off); off += (size_t)N_ROWS * D_DIM * 2;
    unsigned short* Zb  = (unsigned short*)(ws + off); off += (size_t)M_PAD * D_DIM * 2;
    unsigned short* WbT = (unsigned short*)(ws + off); off += (size_t)Y_DIM * M_PAD * 2;
    float* xsq = (float*)(ws + off); off += (size_t)N_ROWS * 4;
    float* zsq = (float*)(ws + off); off += (size_t)M_PAD * 4;
    // total ws use: ~68.7 MB

    hipMemsetAsync(d_out, 0, (size_t)out_size * sizeof(float), stream);
    cast_rows_kernel<<<N_ROWS, 256, 0, stream>>>(X, Xb, xsq, N_ROWS);
    cast_rows_kernel<<<M_PAD, 256, 0, stream>>>(Z, Zb, zsq, M_CENT);
    cast_wT_kernel<<<dim3(M_PAD / 32, Y_DIM / 32), 256, 0, stream>>>(W, WbT);
    fused_kernel<<<dim3(N_ROWS / BM, MSPLIT), 256, 0, stream>>>(
        Xb, Zb, WbT, xsq, zsq, bw, out);
}

// Round 13
// 737.392 us; speedup vs baseline: 1.0782x; 1.0782x over previous
//
#include <hip/hip_runtime.h>
#include <stdint.h>

// Problem constants
#define N_ROWS 8192
#define D_DIM  1024
#define M_CENT 20000
#define M_PAD  20224          // 79 * 256
#define M_TILES 79            // 256-wide center tiles
#define Y_DIM  256
#define BM 64                 // rows of X per block (2 blocks/CU geometry)
#define BN 256                // centers per M-iteration (wave tile 64x64)
#define BK 64                 // K-chunk of D
#define NCHUNK 16             // D_DIM / BK
#define MSPLIT 8
#define TILES_PER_SPLIT 10    // ceil(79/8)
#define LDSP_STRIDE 264       // 256 + 8 pad: 33 16B-slots/row == 1 mod 8 -> conflict-free

// LDS layout (u16 element offsets into lds_all), R8's HW-verified footprint:
//   buf0: [0, 20480)        = X[64][64] (4096) + Z[256][64] (16384)
//   buf1: [20480, 40960)    = same, second stage buffer
//   p   : [20480, 37376)    = P[64][264] (16896) -- aliases buf1 ONLY; buf0
//                             stays free so next-tile chunk-0 prefetch flies
//                             during Phases 2-3.
// Total 40960 elem = 81920 B = EXACTLY half of 160KB -> 2 blocks/CU
// (R7/R8 HW-verified: LDS_Block_Size=81920, Occupancy 22% = 2 blocks/CU).
#define BUFE 20480            // elements per stage buffer
#define ZOFF 4096             // Z offset within a buffer
#define POFF 20480            // p region start (== buf1)

typedef __attribute__((ext_vector_type(4))) float  f32x4;
typedef __attribute__((ext_vector_type(8))) __bf16 bf16x8;

__device__ __forceinline__ unsigned short f2bf(float f) {
    union { float f; unsigned u; } v; v.f = f;
    unsigned u = v.u;
    u += 0x7FFFu + ((u >> 16) & 1u);   // RNE
    return (unsigned short)(u >> 16);
}

// async global->LDS, 16B per lane. LDS dest must be wave-uniform base + lane*16.
__device__ __forceinline__ void gll16(void* lds, const void* g) {
    __builtin_amdgcn_global_load_lds(
        (const __attribute__((address_space(1))) void*)g,
        (__attribute__((address_space(3))) void*)lds, 16, 0, 0);
}

// cast fp32 rows -> bf16, compute fp32 row sum-of-squares; pad rows -> zeros
__global__ void cast_rows_kernel(const float* __restrict__ src,
                                 unsigned short* __restrict__ dst,
                                 float* __restrict__ sq, int nrows_valid) {
    int row = blockIdx.x;
    int t = threadIdx.x;  // 256 threads, 4 floats each = 1024 = D_DIM
    float s = 0.f;
    if (row < nrows_valid) {
        float4 v = ((const float4*)(src + (size_t)row * D_DIM))[t];
        s = v.x * v.x + v.y * v.y + v.z * v.z + v.w * v.w;
        ushort4 o;
        o.x = f2bf(v.x); o.y = f2bf(v.y); o.z = f2bf(v.z); o.w = f2bf(v.w);
        ((ushort4*)(dst + (size_t)row * D_DIM))[t] = o;
    } else {
        ((ushort4*)(dst + (size_t)row * D_DIM))[t] = make_ushort4(0, 0, 0, 0);
    }
    __shared__ float red[4];
    for (int off = 32; off; off >>= 1) s += __shfl_down(s, off, 64);
    if ((t & 63) == 0) red[t >> 6] = s;
    __syncthreads();
    if (t == 0) sq[row] = red[0] + red[1] + red[2] + red[3];
}

// W [M][Y] fp32 -> WT [Y][M_PAD] bf16, pad rows (centers >= M_CENT) -> 0
__global__ void cast_wT_kernel(const float* __restrict__ w,
                               unsigned short* __restrict__ wT) {
    __shared__ float tile[32][33];
    int k0 = blockIdx.x * 32;   // center dim
    int y0 = blockIdx.y * 32;   // Y dim
    int tx = threadIdx.x & 31;
    int ty = threadIdx.x >> 5;  // 0..7
    #pragma unroll
    for (int i = 0; i < 4; ++i) {
        int k = k0 + ty + i * 8;
        float v = (k < M_CENT) ? w[(size_t)k * Y_DIM + y0 + tx] : 0.f;
        tile[tx][ty + i * 8] = v;     // tile[y_local][k_local]
    }
    __syncthreads();
    #pragma unroll
    for (int i = 0; i < 4; ++i) {
        int yl = ty + i * 8;
        wT[(size_t)(y0 + yl) * M_PAD + k0 + tx] = f2bf(tile[yl][tx]);
    }
}

// ---------------------------------------------------------------------------
// R15 = R8 + NORM-SEEDED ACCUMULATOR (post-mortems R9/R12/R13/R14: the BK=32
// family trades spill for barrier overhead -- all land 677-703us; R8 (BK=64,
// 593us) is the best structure, its only defect the ~200MB Phase-2 spill of
// the norm operands xq[16]+zq[4].  Instead of finding those operands a home
// (regs -> spill R8; LDS gap -> worse R9; dedicated LDS -> no fit R7),
// ELIMINATE them: d2 = xsq + zsq - 2S, so seed
//     S_init[i][j] = -(xsq[i] + zsq[j]) / 2
// and after Phase 1, d2 = -2*S.  Phase 2 has NO operands -- no loads, no
// norm registers, ~20 fewer live regs at the old spill point; seed loads
// sit at the tile top (minimal pressure), die before CHUNK(0), and their
// compiler wait only sweeps the tile-boundary prefetch issued a whole
// Phase-2+3 earlier (long landed).  vmcnt counting unaffected (norm loads
// are older than the stage; in-order retirement).  Numerics: same fp32
// 3-term sum, reordered -- within bf16-floor tolerance.
//  - Everything else byte-identical to R8:
//    * R2 geometry: BM=64, 4 waves, MSPLIT=8, 1024 blocks, 2 resident/CU.
//    * Counted-vmcnt raw-barrier pipeline (T3+T4, HW-verified):
//        barA -> STAGE(next buf, 10 gll16) -> s_waitcnt vmcnt(10) -> barB
//        -> ds_read frags -> 32 MFMA; vmcnt never drains to 0 in phase 1;
//      chunk-15 stages next tile's chunk-0 into buf0 (lands in Phases 2-3).
//    * v_sqrt_f32 inline; launch_bounds(256,2).
//  Sentinels: WRITE ~75MB / FETCH ~450MB = spill dead (primary).
//  Fork: WRITE clean but dur >= 590 -> spill was never critical-path; the
//  phase-serialized structure is the ~590 floor -> phase-ablation next.
// ---------------------------------------------------------------------------

#define STAGE(PAR, M0, KBASE) do {                                            \
    _Pragma("unroll")                                                         \
    for (int i_ = 0; i_ < 2; ++i_) {          /* X: 512 16B-chunks */         \
        int lin_ = t + i_ * 256;                                              \
        int row_ = lin_ >> 3, c_ = lin_ & 7;                                  \
        gll16(&lds_all[(PAR) * BUFE + lin_ * 8],                              \
              Xb + (size_t)(row0 + row_) * D_DIM + (KBASE) +                  \
                  ((c_ ^ (row_ & 7)) * 8));                                   \
    }                                                                         \
    _Pragma("unroll")                                                         \
    for (int i_ = 0; i_ < 8; ++i_) {          /* Z: 2048 16B-chunks */        \
        int lin_ = t + i_ * 256;                                              \
        int row_ = lin_ >> 3, c_ = lin_ & 7;                                  \
        gll16(&lds_all[(PAR) * BUFE + ZOFF + lin_ * 8],                       \
              Zb + (size_t)((M0) + row_) * D_DIM + (KBASE) +                  \
                  ((c_ ^ (row_ & 7)) * 8));                                   \
    } } while (0)

// One K-chunk.  PAR literal 0/1.  On entry: [stage(kc)x10] outstanding
// (issued one chunk earlier); buf[PAR^1]'s readers all passed barA.
// vmcnt(10) keeps the 10 JUST-ISSUED ops outstanding and drains everything
// older (stage(kc) + any stray scalar loads) -- robust counting.
#define CHUNK(PAR, M0N, KBN) do {                                             \
    asm volatile("" ::: "memory");                                            \
    __builtin_amdgcn_s_barrier();          /* barA: buf[PAR^1] free */        \
    asm volatile("" ::: "memory");                                            \
    STAGE(PAR ^ 1, M0N, KBN);                                                 \
    __builtin_amdgcn_sched_barrier(0);                                        \
    asm volatile("s_waitcnt vmcnt(10)" ::: "memory"); /* stage(kc) done */    \
    __builtin_amdgcn_s_barrier();          /* barB: everyone's stage done */  \
    asm volatile("" ::: "memory");                                            \
    _Pragma("unroll")                                                         \
    for (int kt_ = 0; kt_ < 2; ++kt_) {                                       \
        const int sw_ = ((kt_ * 4 + quad) ^ cx) * 8;                          \
        bf16x8 a_[4], b_[4];                                                  \
        _Pragma("unroll")                                                     \
        for (int it_ = 0; it_ < 4; ++it_)                                     \
            a_[it_] = *(const bf16x8*)&lds_all[(PAR) * BUFE +                 \
                (it_ * 16 + l16) * BK + sw_];                                 \
        _Pragma("unroll")                                                     \
        for (int jt_ = 0; jt_ < 4; ++jt_)                                     \
            b_[jt_] = *(const bf16x8*)&lds_all[(PAR) * BUFE + ZOFF +          \
                (wave * 64 + jt_ * 16 + l16) * BK + sw_];                     \
        __builtin_amdgcn_s_setprio(1);                                        \
        _Pragma("unroll")                                                     \
        for (int it_ = 0; it_ < 4; ++it_)                                     \
            _Pragma("unroll")                                                 \
            for (int jt_ = 0; jt_ < 4; ++jt_)                                 \
                S[it_ * 4 + jt_] = __builtin_amdgcn_mfma_f32_16x16x32_bf16(   \
                    a_[it_], b_[jt_], S[it_ * 4 + jt_], 0, 0, 0);             \
        __builtin_amdgcn_s_setprio(0);                                        \
    } } while (0)

__global__ void __launch_bounds__(256, 2)
fused_kernel(const unsigned short* __restrict__ Xb,
             const unsigned short* __restrict__ Zb,
             const unsigned short* __restrict__ WbT,
             const float* __restrict__ xsq,
             const float* __restrict__ zsq,
             const int* __restrict__ bwp,
             float* __restrict__ out) {
    __shared__ unsigned short lds_all[2 * BUFE];   // EXACTLY 81920 B

    const int t    = threadIdx.x;
    const int wave = t >> 6;      // 0..3: m-slab (phase1 B, phase3 y-slab)
    const int lane = t & 63;
    const int quad = lane >> 4;
    const int l16  = lane & 15;
    const int cx   = l16 & 7;     // row&7 of every frag row this lane touches

    const int row0 = blockIdx.x * BM;          // R2 known-good mapping
    const int mt0  = blockIdx.y * TILES_PER_SPLIT;
    int mt_end = mt0 + TILES_PER_SPLIT;
    if (mt_end > M_TILES) mt_end = M_TILES;

    // bandwidth: int32 per harness convention (Python int 10); tolerate float bits too
    int bwi = *bwp;
    float bw;
    if (bwi > 0 && bwi < 1000000) bw = (float)bwi;
    else { union { int i; float f; } u; u.i = bwi; bw = u.f; }
    const float inv_bw = 1.0f / bw;

    const f32x4 vzero = {0.f, 0.f, 0.f, 0.f};
    f32x4 Oacc[16];
    #pragma unroll
    for (int i = 0; i < 16; ++i) Oacc[i] = vzero;

    // prologue: stage (tile mt0, chunk 0) -> buf0
    STAGE(0, mt0 * BN, 0);
    __builtin_amdgcn_sched_barrier(0);

    for (int mt = mt0; mt < mt_end; ++mt) {
        const int m0 = mt * BN;
        // last tile of split prefetches itself (valid mem, unused)
        const int m0next = (mt + 1 < mt_end) ? m0 + BN : m0;

        // ---- NORM-SEEDED ACCUMULATOR (R15) ----
        // Load norms at tile top (L2-hot; the implicit wait sweeps only the
        // long-landed tile-boundary prefetch) and fold them into S's init:
        //   S_init = -(xsq[row] + zsq[col])/2  =>  d2 = -2*S after Phase 1.
        // xq/zq die HERE -- nothing norm-related is live in Phases 1-3.
        f32x4 S[16];
        {
            f32x4 xq[4];
            #pragma unroll
            for (int it = 0; it < 4; ++it)
                xq[it] = *(const f32x4*)(xsq + row0 + it * 16 + quad * 4);
            float zq[4];
            #pragma unroll
            for (int jt = 0; jt < 4; ++jt)
                zq[jt] = zsq[m0 + wave * 64 + jt * 16 + l16];
            #pragma unroll
            for (int it = 0; it < 4; ++it)
                #pragma unroll
                for (int jt = 0; jt < 4; ++jt)
                    #pragma unroll
                    for (int r = 0; r < 4; ++r)
                        S[it * 4 + jt][r] = -0.5f * (xq[it][r] + zq[jt]);
        }

        // -------- Phase 1: S[64x256] = seed + X * Z^T, counted-vmcnt pipe --
        // chunk kc reads buf[kc&1]; stages kc+1 into buf[(kc+1)&1].
        // kc=15 stages NEXT TILE's chunk 0 into buf0 (disjoint from p),
        // landing during Phases 2-3 -> no drain at tile boundary.
        #pragma unroll 1
        for (int kc = 0; kc < NCHUNK; kc += 2) {
            const bool last = (kc + 2 == NCHUNK);
            CHUNK(0, m0, (kc + 1) * BK);
            CHUNK(1, last ? m0next : m0, last ? 0 : (kc + 2) * BK);
        }

        // phase1 -> phase2: all buf1 readers done before p overwrites it
        asm volatile("" ::: "memory");
        __builtin_amdgcn_s_barrier();
        asm volatile("" ::: "memory");

        // -------- Phase 2: P = exp(-sqrt(max(-2S,0))/bw) -> p (bf16) ------
        // No operands: d2 comes straight from the seeded accumulator.
        #pragma unroll
        for (int it = 0; it < 4; ++it) {
            #pragma unroll
            for (int jt = 0; jt < 4; ++jt) {
                f32x4 s4 = S[it * 4 + jt];
                const int col = wave * 64 + jt * 16 + l16;
                #pragma unroll
                for (int r = 0; r < 4; ++r) {
                    const int row = it * 16 + quad * 4 + r;   // C-layout
                    float d2 = fmaxf(-2.0f * s4[r], 0.f);
                    float d;
                    asm("v_sqrt_f32 %0, %1" : "=v"(d) : "v"(d2));
                    float p = __expf(-d * inv_bw);
                    lds_all[POFF + row * LDSP_STRIDE + col] = f2bf(p);
                }
            }
        }
        // P-write -> P-read: LDS-only drain; buf0 prefetch stays in flight
        asm volatile("s_waitcnt lgkmcnt(0)" ::: "memory");
        __builtin_amdgcn_s_barrier();
        asm volatile("" ::: "memory");

        // -------- Phase 3: O += P[64x256] * Wtile[256x256] --------
        #pragma unroll
        for (int ks = 0; ks < 8; ++ks) {
            const int koff = ks * 32 + quad * 8;
            bf16x8 a[4], b[4];
            #pragma unroll
            for (int rt = 0; rt < 4; ++rt)
                a[rt] = *(const bf16x8*)&lds_all[POFF +
                    (rt * 16 + l16) * LDSP_STRIDE + koff];
            #pragma unroll
            for (int ct = 0; ct < 4; ++ct) {
                const int y = wave * 64 + ct * 16 + l16;
                b[ct] = *(const bf16x8*)(WbT + (size_t)y * M_PAD + m0 + koff);
            }
            __builtin_amdgcn_s_setprio(1);
            #pragma unroll
            for (int rt = 0; rt < 4; ++rt)
                #pragma unroll
                for (int ct = 0; ct < 4; ++ct)
                    Oacc[rt * 4 + ct] = __builtin_amdgcn_mfma_f32_16x16x32_bf16(
                        a[rt], b[ct], Oacc[rt * 4 + ct], 0, 0, 0);
            __builtin_amdgcn_s_setprio(0);
        }
        // next tile's CHUNK(0) barA separates these p reads from the next
        // stage writes into buf1 (p ds_reads are lgkm-drained pre-MFMA).
    }

    // drain the dangling last-tile prefetch before LDS is released
    asm volatile("s_waitcnt vmcnt(0)" ::: "memory");

    // -------- epilogue: accumulate M-splits via device-scope fp32 atomics ----
    #pragma unroll
    for (int rt = 0; rt < 4; ++rt) {
        #pragma unroll
        for (int ct = 0; ct < 4; ++ct) {
            f32x4 v = Oacc[rt * 4 + ct];
            const int y = wave * 64 + ct * 16 + l16;
            #pragma unroll
            for (int r = 0; r < 4; ++r) {
                const int row = row0 + rt * 16 + quad * 4 + r;
                atomicAdd(&out[(size_t)row * Y_DIM + y], v[r]);
            }
        }
    }
}

extern "C" void kernel_launch(void* const* d_in, const int* in_sizes, int n_in,
                              void* d_out, int out_size, void* d_ws, size_t ws_size,
                              hipStream_t stream) {
    const float* X = (const float*)d_in[0];
    const float* Z = (const float*)d_in[1];
    const float* W = (const float*)d_in[2];
    const int*  bw = (const int*)d_in[3];
    float* out = (float*)d_out;

    char* ws = (char*)d_ws;
    size_t off = 0;
    unsigned short* Xb  = (unsigned short*)(ws + off); off += (size_t)N_ROWS * D_DIM * 2;
    unsigned short* Zb  = (unsigned short*)(ws + off); off += (size_t)M_PAD * D_DIM * 2;
    unsigned short* WbT = (unsigned short*)(ws + off); off += (size_t)Y_DIM * M_PAD * 2;
    float* xsq = (float*)(ws + off); off += (size_t)N_ROWS * 4;
    float* zsq = (float*)(ws + off); off += (size_t)M_PAD * 4;
    // total ws use: ~68.7 MB

    hipMemsetAsync(d_out, 0, (size_t)out_size * sizeof(float), stream);
    cast_rows_kernel<<<N_ROWS, 256, 0, stream>>>(X, Xb, xsq, N_ROWS);
    cast_rows_kernel<<<M_PAD, 256, 0, stream>>>(Z, Zb, zsq, M_CENT);
    cast_wT_kernel<<<dim3(M_PAD / 32, Y_DIM / 32), 256, 0, stream>>>(W, WbT);
    fused_kernel<<<dim3(N_ROWS / BM, MSPLIT), 256, 0, stream>>>(
        Xb, Zb, WbT, xsq, zsq, bw, out);
}